// Round 4
// baseline (491.429 us; speedup 1.0000x reference)
//
#include <hip/hip_runtime.h>

#define NTOK     131072
#define KCODES   1024
#define DIM      64
#define TAU_S    2e-3f
#define FLAG_CAP 12288

typedef unsigned short ushort_t;
typedef unsigned int uint_t;
typedef __attribute__((ext_vector_type(8))) short short8;
typedef __attribute__((ext_vector_type(4))) float f32x4;
typedef __attribute__((ext_vector_type(4))) float nf32x4;
typedef __attribute__((ext_vector_type(2))) float nf32x2;

// ws layout (bytes):
//      0 : counts u32[1024]
//   4096 : loss double
//   4104 : flag_count u32
//   4112 : wsq float[1024]            (..8208)
//   8208 : Wh ushort[65536]           (..139280)
// 139280 : Wl ushort[65536]           (..270352)
// 270352 : flags int[4*FLAG_CAP]      (..466960)  {tok, oldidx, dq_bits, pad}
// 466960 : idx_g ushort[131072]       (..729104)

__device__ inline ushort_t f2bf(float f) {
    uint_t u = __float_as_uint(f);
    return (ushort_t)((u + 0x7FFFu + ((u >> 16) & 1u)) >> 16);
}
__device__ inline float bf2f(ushort_t h) { return __uint_as_float(((uint_t)h) << 16); }

__device__ inline void pack8(float4 p, float4 q, short8& h, short8& l) {
    float v[8] = {p.x, p.y, p.z, p.w, q.x, q.y, q.z, q.w};
#pragma unroll
    for (int j = 0; j < 8; ++j) {
        ushort_t hb = f2bf(v[j]);
        float hf = bf2f(hb);
        ushort_t lb = f2bf(v[j] - hf);
        h[j] = (short)hb;
        l[j] = (short)lb;
    }
}

// ---- prep: split W into bf16 hi/lo, compute wsq ----
__global__ __launch_bounds__(256) void vq_prep(const float* __restrict__ W,
                                               ushort_t* __restrict__ Wh,
                                               ushort_t* __restrict__ Wl,
                                               float* __restrict__ wsq) {
    int e = blockIdx.x * 256 + threadIdx.x;  // 65536 elements
    float w = W[e];
    ushort_t hb = f2bf(w);
    float hf = bf2f(hb);
    ushort_t lb = f2bf(w - hf);
    Wh[e] = hb; Wl[e] = lb;
    float sq = w * w;
#pragma unroll
    for (int off = 32; off >= 1; off >>= 1) sq += __shfl_xor(sq, off, 64);
    if ((threadIdx.x & 63) == 0) wsq[e >> 6] = sq;  // one wave == one row of 64
}

// ---- argmin: bf16-split MFMA scan, 64 codes per iteration ----
__global__ __launch_bounds__(256) void vq_argmin(
    const float* __restrict__ X,
    const ushort_t* __restrict__ Wh, const ushort_t* __restrict__ Wl,
    const float* __restrict__ wsq, ushort_t* __restrict__ idx_g,
    uint_t* __restrict__ counts, double* __restrict__ loss_acc,
    uint_t* __restrict__ flag_cnt, int* __restrict__ flags)
{
    const int tid  = threadIdx.x;
    const int lane = tid & 63;
    const int wv   = tid >> 6;
    const int row  = lane & 15;   // A-fragment row (token within wave tile)
    const int ks   = lane >> 4;   // k-slice
    const int TB   = blockIdx.x * 64;
    const int WB   = TB + wv * 16;

    // A tile: 16 tokens x 64 dims -> bf16 hi/lo frags, reused for all codes
    const float* xr = X + (size_t)(WB + row) * DIM + ks * 8;
    float4 a0 = *(const float4*)(xr);
    float4 a1 = *(const float4*)(xr + 4);
    float4 a2 = *(const float4*)(xr + 32);
    float4 a3 = *(const float4*)(xr + 36);

    float xsq = a0.x*a0.x + a0.y*a0.y + a0.z*a0.z + a0.w*a0.w
              + a1.x*a1.x + a1.y*a1.y + a1.z*a1.z + a1.w*a1.w
              + a2.x*a2.x + a2.y*a2.y + a2.z*a2.z + a2.w*a2.w
              + a3.x*a3.x + a3.y*a3.y + a3.z*a3.z + a3.w*a3.w;
    xsq += __shfl_xor(xsq, 16, 64);
    xsq += __shfl_xor(xsq, 32, 64);   // full 64-dim xsq of token row (lane&15)

    short8 xh0, xl0, xh1, xl1;
    pack8(a0, a1, xh0, xl0);
    pack8(a2, a3, xh1, xl1);

    __shared__ float s_xsq[4][16];
    __shared__ float s_loss[4];
    if (lane < 16) s_xsq[wv][lane] = xsq;

    // track s = dot - wsq/2 (maximize); dist = xsq - 2*s
    float m1[4], m2[4]; int i1[4];
#pragma unroll
    for (int r = 0; r < 4; ++r) { m1[r] = -3.4e38f; m2[r] = -3.4e38f; i1[r] = 0; }

    for (int cb = 0; cb < KCODES; cb += 64) {
        // batch-load B frags for 4 code groups (16 x 16B loads in flight)
        short8 bh0[4], bh1[4], bl0[4], bl1[4];
        float c0[4];
#pragma unroll
        for (int j = 0; j < 4; ++j) {
            const int col = cb + 16 * j + row;
            const ushort_t* whp = Wh + (size_t)col * DIM + ks * 8;
            const ushort_t* wlp = Wl + (size_t)col * DIM + ks * 8;
            bh0[j] = *(const short8*)(whp);
            bh1[j] = *(const short8*)(whp + 32);
            bl0[j] = *(const short8*)(wlp);
            bl1[j] = *(const short8*)(wlp + 32);
            c0[j]  = -0.5f * wsq[col];
        }
        const int cc0 = cb + row;
#pragma unroll
        for (int j = 0; j < 4; ++j) {
            f32x4 acc;
            acc[0] = c0[j]; acc[1] = c0[j]; acc[2] = c0[j]; acc[3] = c0[j];
            acc = __builtin_amdgcn_mfma_f32_16x16x32_bf16(xh0, bh0[j], acc, 0, 0, 0);
            acc = __builtin_amdgcn_mfma_f32_16x16x32_bf16(xh1, bh1[j], acc, 0, 0, 0);
            acc = __builtin_amdgcn_mfma_f32_16x16x32_bf16(xh0, bl0[j], acc, 0, 0, 0);
            acc = __builtin_amdgcn_mfma_f32_16x16x32_bf16(xh1, bl1[j], acc, 0, 0, 0);
            acc = __builtin_amdgcn_mfma_f32_16x16x32_bf16(xl0, bh0[j], acc, 0, 0, 0);
            acc = __builtin_amdgcn_mfma_f32_16x16x32_bf16(xl1, bh1[j], acc, 0, 0, 0);
            const int cc = cc0 + 16 * j;
#pragma unroll
            for (int r = 0; r < 4; ++r) {
                float v = acc[r];
                bool gt = v > m1[r];                      // strict: ties keep lower idx
                m2[r] = fmaxf(fminf(v, m1[r]), m2[r]);
                i1[r] = gt ? cc : i1[r];
                m1[r] = fmaxf(v, m1[r]);
            }
        }
    }

    // merge across the 16 lanes sharing group g = lane>>4 (code residues)
#pragma unroll
    for (int mask = 1; mask <= 8; mask <<= 1) {
#pragma unroll
        for (int r = 0; r < 4; ++r) {
            float v1 = __shfl_xor(m1[r], mask, 64);
            int   j1 = __shfl_xor(i1[r], mask, 64);
            float v2 = __shfl_xor(m2[r], mask, 64);
            bool take = (v1 > m1[r]) || (v1 == m1[r] && j1 < i1[r]);
            m2[r] = take ? fmaxf(m1[r], v2) : fmaxf(v1, m2[r]);
            m1[r] = take ? v1 : m1[r];
            i1[r] = take ? j1 : i1[r];
        }
    }

    float lsum = 0.f;
    if ((lane & 15) == 0) {
        const int g = lane >> 4;
#pragma unroll
        for (int r = 0; r < 4; ++r) {
            const int trow = g * 4 + r;
            const int t = WB + trow;
            idx_g[t] = (ushort_t)i1[r];
            atomicAdd(&counts[i1[r]], 1u);
            float dq = s_xsq[wv][trow] - 2.f * m1[r];
            lsum += dq;
            if (m1[r] - m2[r] < TAU_S) {                  // near-tie -> fp64 recheck
                uint_t pos = atomicAdd(flag_cnt, 1u);
                if (pos < FLAG_CAP) {
                    flags[4 * pos + 0] = t;
                    flags[4 * pos + 1] = i1[r];
                    flags[4 * pos + 2] = __float_as_int(dq);
                }
            }
        }
    }
    lsum += __shfl_xor(lsum, 16, 64);
    lsum += __shfl_xor(lsum, 32, 64);
    if (lane == 0) s_loss[wv] = lsum;
    __syncthreads();
    if (tid == 0)
        atomicAdd(loss_acc, (double)(s_loss[0] + s_loss[1] + s_loss[2] + s_loss[3]));
}

// ---- store: pure streaming construction of encodings + quantized ----
__global__ __launch_bounds__(256) void vq_store(
    const ushort_t* __restrict__ idx_g, const float* __restrict__ W,
    float* __restrict__ out)
{
    const int tid = threadIdx.x;
    const int TB  = blockIdx.x * 64;
    __shared__ int s_idx[64];
    if (tid < 64) s_idx[tid] = idx_g[TB + tid];
    __syncthreads();

    // encodings: base = out + 2 + NTOK*DIM  (byte addr == 8 mod 16)
    float* enc = out + 2 + (size_t)NTOK * DIM + (size_t)TB * KCODES;
    if (tid < 255) {
        const int c = 2 + 4 * tid;                 // 16B-aligned interior
        float* p = enc + c;
        for (int r = 0; r < 64; ++r) {
            const int k = s_idx[r] - c;
            nf32x4 v;
            v.x = (k == 0) ? 1.f : 0.f;
            v.y = (k == 1) ? 1.f : 0.f;
            v.z = (k == 2) ? 1.f : 0.f;
            v.w = (k == 3) ? 1.f : 0.f;
            __builtin_nontemporal_store(v, (nf32x4*)(p));
            p += KCODES;
        }
    } else {                                       // head (cols 0,1) + tail (1022,1023)
        float* p = enc;
        for (int r = 0; r < 64; ++r) {
            const int idx = s_idx[r];
            nf32x2 h, t;
            h.x = (idx == 0)    ? 1.f : 0.f;
            h.y = (idx == 1)    ? 1.f : 0.f;
            t.x = (idx == 1022) ? 1.f : 0.f;
            t.y = (idx == 1023) ? 1.f : 0.f;
            __builtin_nontemporal_store(h, (nf32x2*)(p));
            __builtin_nontemporal_store(t, (nf32x2*)(p + 1022));
            p += KCODES;
        }
    }

    // quantized rows (out[1..]): 4B-aligned only -> scalar NT, coalesced
    for (int i = tid; i < 64 * DIM; i += 256) {
        const int r = i >> 6, c = i & 63;
        const float w = W[(size_t)s_idx[r] * DIM + c];
        __builtin_nontemporal_store(w, out + 1 + (size_t)(TB + r) * DIM + c);
    }
}

// ---- refine: fp64 full rescan of flagged (near-tie) tokens, patch outputs ----
__global__ __launch_bounds__(256) void vq_refine(
    const float* __restrict__ X, const float* __restrict__ W,
    float* __restrict__ out, uint_t* __restrict__ counts,
    double* __restrict__ loss_acc, const uint_t* __restrict__ flag_cnt,
    const int* __restrict__ flags)
{
    const int tid = threadIdx.x;
    const int lane = tid & 63;
    const int wv = tid >> 6;
    uint_t n = *flag_cnt; if (n > FLAG_CAP) n = FLAG_CAP;
    __shared__ float sx[DIM];
    __shared__ double sbest[4];
    __shared__ int sbi[4];
    for (uint_t e = blockIdx.x; e < n; e += gridDim.x) {
        const int t   = flags[4 * e + 0];
        const int old = flags[4 * e + 1];
        const float dq_old = __int_as_float(flags[4 * e + 2]);
        __syncthreads();
        if (tid < DIM) sx[tid] = X[(size_t)t * DIM + tid];
        __syncthreads();
        double best = 1e300; int bi = KCODES;
        for (int k = 0; k < 4; ++k) {
            const int c = tid * 4 + k;
            const float* wr = W + (size_t)c * DIM;
            double d = 0.0;
            for (int dd = 0; dd < DIM; ++dd) {
                double diff = (double)sx[dd] - (double)wr[dd];
                d += diff * diff;
            }
            if (d < best) { best = d; bi = c; }
        }
#pragma unroll
        for (int mask = 1; mask <= 32; mask <<= 1) {
            double db = __shfl_xor(best, mask, 64);
            int    ib = __shfl_xor(bi, mask, 64);
            if (db < best || (db == best && ib < bi)) { best = db; bi = ib; }
        }
        if (lane == 0) { sbest[wv] = best; sbi[wv] = bi; }
        __syncthreads();
        if (tid == 0) {
            for (int w = 1; w < 4; ++w)
                if (sbest[w] < best || (sbest[w] == best && sbi[w] < bi)) { best = sbest[w]; bi = sbi[w]; }
            atomicAdd(loss_acc, best - (double)dq_old);  // exact-ify loss term
            if (bi != old) {
                atomicSub(&counts[old], 1u);
                atomicAdd(&counts[bi], 1u);
                float* encp = out + 2 + (size_t)NTOK * DIM + (size_t)t * KCODES;
                encp[old] = 0.f; encp[bi] = 1.f;
                float* q = out + 1 + (size_t)t * DIM;
                for (int dd = 0; dd < DIM; ++dd) q[dd] = W[(size_t)bi * DIM + dd];
            }
        }
    }
}

__global__ __launch_bounds__(256) void vq_finalize(
    const uint_t* __restrict__ counts, const double* __restrict__ loss_acc,
    float* __restrict__ out)
{
    int tid = threadIdx.x;
    float h = 0.f;
    for (int i = tid; i < KCODES; i += 256) {
        float p = (float)counts[i] * (1.0f / (float)NTOK);
        h += p * logf(p + 1e-10f);
    }
    __shared__ float red[4];
#pragma unroll
    for (int off = 32; off >= 1; off >>= 1) h += __shfl_down(h, off, 64);
    if ((tid & 63) == 0) red[tid >> 6] = h;
    __syncthreads();
    if (tid == 0) {
        float ht = red[0] + red[1] + red[2] + red[3];
        out[(size_t)NTOK * DIM + 1] = expf(-ht);                        // perplexity
        out[0] = 0.25f * (float)(loss_acc[0] / ((double)NTOK * DIM));   // loss
    }
}

extern "C" void kernel_launch(void* const* d_in, const int* in_sizes, int n_in,
                              void* d_out, int out_size, void* d_ws, size_t ws_size,
                              hipStream_t stream) {
    const float* X = (const float*)d_in[0];
    const float* W = (const float*)d_in[1];
    float* out = (float*)d_out;
    uint_t*   counts   = (uint_t*)d_ws;
    double*   loss_acc = (double*)((char*)d_ws + 4096);
    uint_t*   flag_cnt = (uint_t*)((char*)d_ws + 4104);
    float*    wsq      = (float*)((char*)d_ws + 4112);
    ushort_t* Wh       = (ushort_t*)((char*)d_ws + 8208);
    ushort_t* Wl       = (ushort_t*)((char*)d_ws + 139280);
    int*      flags    = (int*)((char*)d_ws + 270352);
    ushort_t* idx_g    = (ushort_t*)((char*)d_ws + 466960);

    (void)hipMemsetAsync(d_ws, 0, 4112, stream);  // counts + loss + flag_cnt
    vq_prep<<<KCODES * DIM / 256, 256, 0, stream>>>(W, Wh, Wl, wsq);
    vq_argmin<<<NTOK / 64, 256, 0, stream>>>(X, Wh, Wl, wsq, idx_g,
                                             counts, loss_acc, flag_cnt, flags);
    vq_store<<<NTOK / 64, 256, 0, stream>>>(idx_g, W, out);
    vq_refine<<<256, 256, 0, stream>>>(X, W, out, counts, loss_acc, flag_cnt, flags);
    vq_finalize<<<1, 256, 0, stream>>>(counts, loss_acc, out);
}

// Round 5
// 474.118 us; speedup vs baseline: 1.0365x; 1.0365x over previous
//
#include <hip/hip_runtime.h>

#define NTOK     131072
#define KCODES   1024
#define DIM      64
#define TAU_S    2e-3f
#define FLAG_CAP 12288

typedef unsigned short ushort_t;
typedef unsigned int uint_t;
typedef __attribute__((ext_vector_type(8))) short short8;
typedef __attribute__((ext_vector_type(4))) float f32x4;
typedef __attribute__((ext_vector_type(4))) float nf32x4;
typedef __attribute__((ext_vector_type(2))) float nf32x2;

// ws layout (bytes):
//      0 : counts u32[1024]                       (..4096)
//   4096 : flag_cnt u32 (+pad)                    (..4112)
//   4112 : lossA f32[8192]  per-wave partials     (..36880)
//  36880 : lossB f64[256]   refine partials       (..38928)
//  38928 : wsq f32[1024]                          (..43024)
//  43024 : Wh ushort[65536]                       (..174096)
// 174096 : Wl ushort[65536]                       (..305168)
// 305168 : flags int[4*FLAG_CAP]                  (..501776)
// 501776 : idx_g ushort[131072]                   (..763920)

__device__ inline ushort_t f2bf(float f) {
    uint_t u = __float_as_uint(f);
    return (ushort_t)((u + 0x7FFFu + ((u >> 16) & 1u)) >> 16);
}
__device__ inline float bf2f(ushort_t h) { return __uint_as_float(((uint_t)h) << 16); }

__device__ inline void pack8(float4 p, float4 q, short8& h, short8& l) {
    float v[8] = {p.x, p.y, p.z, p.w, q.x, q.y, q.z, q.w};
#pragma unroll
    for (int j = 0; j < 8; ++j) {
        ushort_t hb = f2bf(v[j]);
        float hf = bf2f(hb);
        ushort_t lb = f2bf(v[j] - hf);
        h[j] = (short)hb;
        l[j] = (short)lb;
    }
}

// ---- prep: split W into bf16 hi/lo, compute wsq ----
__global__ __launch_bounds__(256) void vq_prep(const float* __restrict__ W,
                                               ushort_t* __restrict__ Wh,
                                               ushort_t* __restrict__ Wl,
                                               float* __restrict__ wsq) {
    int e = blockIdx.x * 256 + threadIdx.x;  // 65536 elements
    float w = W[e];
    ushort_t hb = f2bf(w);
    float hf = bf2f(hb);
    ushort_t lb = f2bf(w - hf);
    Wh[e] = hb; Wl[e] = lb;
    float sq = w * w;
#pragma unroll
    for (int off = 32; off >= 1; off >>= 1) sq += __shfl_xor(sq, off, 64);
    if ((threadIdx.x & 63) == 0) wsq[e >> 6] = sq;  // one wave == one row of 64
}

// ---- argmin: bf16-split MFMA scan, 64 codes per iteration, NO fp64 atomics ----
__global__ __launch_bounds__(256) void vq_argmin(
    const float* __restrict__ X,
    const ushort_t* __restrict__ Wh, const ushort_t* __restrict__ Wl,
    const float* __restrict__ wsq, ushort_t* __restrict__ idx_g,
    uint_t* __restrict__ counts, float* __restrict__ lossA,
    uint_t* __restrict__ flag_cnt, int* __restrict__ flags)
{
    const int tid  = threadIdx.x;
    const int lane = tid & 63;
    const int wv   = tid >> 6;
    const int row  = lane & 15;   // A-fragment row (token within wave tile)
    const int ks   = lane >> 4;   // k-slice
    const int TB   = blockIdx.x * 64;
    const int WB   = TB + wv * 16;

    // A tile: 16 tokens x 64 dims -> bf16 hi/lo frags, reused for all codes
    const float* xr = X + (size_t)(WB + row) * DIM + ks * 8;
    float4 a0 = *(const float4*)(xr);
    float4 a1 = *(const float4*)(xr + 4);
    float4 a2 = *(const float4*)(xr + 32);
    float4 a3 = *(const float4*)(xr + 36);

    float xsq = a0.x*a0.x + a0.y*a0.y + a0.z*a0.z + a0.w*a0.w
              + a1.x*a1.x + a1.y*a1.y + a1.z*a1.z + a1.w*a1.w
              + a2.x*a2.x + a2.y*a2.y + a2.z*a2.z + a2.w*a2.w
              + a3.x*a3.x + a3.y*a3.y + a3.z*a3.z + a3.w*a3.w;
    xsq += __shfl_xor(xsq, 16, 64);
    xsq += __shfl_xor(xsq, 32, 64);   // full 64-dim xsq of token row (lane&15)

    short8 xh0, xl0, xh1, xl1;
    pack8(a0, a1, xh0, xl0);
    pack8(a2, a3, xh1, xl1);

    __shared__ float s_xsq[4][16];
    if (lane < 16) s_xsq[wv][lane] = xsq;   // same-wave producer/consumer only

    // track s = dot - wsq/2 (maximize); dist = xsq - 2*s
    float m1[4], m2[4]; int i1[4];
#pragma unroll
    for (int r = 0; r < 4; ++r) { m1[r] = -3.4e38f; m2[r] = -3.4e38f; i1[r] = 0; }

    for (int cb = 0; cb < KCODES; cb += 64) {
        // batch-load B frags for 4 code groups (16 x 16B loads in flight)
        short8 bh0[4], bh1[4], bl0[4], bl1[4];
        float c0[4];
#pragma unroll
        for (int j = 0; j < 4; ++j) {
            const int col = cb + 16 * j + row;
            const ushort_t* whp = Wh + (size_t)col * DIM + ks * 8;
            const ushort_t* wlp = Wl + (size_t)col * DIM + ks * 8;
            bh0[j] = *(const short8*)(whp);
            bh1[j] = *(const short8*)(whp + 32);
            bl0[j] = *(const short8*)(wlp);
            bl1[j] = *(const short8*)(wlp + 32);
            c0[j]  = -0.5f * wsq[col];
        }
        const int cc0 = cb + row;
#pragma unroll
        for (int j = 0; j < 4; ++j) {
            f32x4 acc;
            acc[0] = c0[j]; acc[1] = c0[j]; acc[2] = c0[j]; acc[3] = c0[j];
            acc = __builtin_amdgcn_mfma_f32_16x16x32_bf16(xh0, bh0[j], acc, 0, 0, 0);
            acc = __builtin_amdgcn_mfma_f32_16x16x32_bf16(xh1, bh1[j], acc, 0, 0, 0);
            acc = __builtin_amdgcn_mfma_f32_16x16x32_bf16(xh0, bl0[j], acc, 0, 0, 0);
            acc = __builtin_amdgcn_mfma_f32_16x16x32_bf16(xh1, bl1[j], acc, 0, 0, 0);
            acc = __builtin_amdgcn_mfma_f32_16x16x32_bf16(xl0, bh0[j], acc, 0, 0, 0);
            acc = __builtin_amdgcn_mfma_f32_16x16x32_bf16(xl1, bh1[j], acc, 0, 0, 0);
            const int cc = cc0 + 16 * j;
#pragma unroll
            for (int r = 0; r < 4; ++r) {
                float v = acc[r];
                bool gt = v > m1[r];                      // strict: ties keep lower idx
                m2[r] = fmaxf(fminf(v, m1[r]), m2[r]);
                i1[r] = gt ? cc : i1[r];
                m1[r] = fmaxf(v, m1[r]);
            }
        }
    }

    // merge across the 16 lanes sharing group g = lane>>4 (code residues)
#pragma unroll
    for (int mask = 1; mask <= 8; mask <<= 1) {
#pragma unroll
        for (int r = 0; r < 4; ++r) {
            float v1 = __shfl_xor(m1[r], mask, 64);
            int   j1 = __shfl_xor(i1[r], mask, 64);
            float v2 = __shfl_xor(m2[r], mask, 64);
            bool take = (v1 > m1[r]) || (v1 == m1[r] && j1 < i1[r]);
            m2[r] = take ? fmaxf(m1[r], v2) : fmaxf(v1, m2[r]);
            m1[r] = take ? v1 : m1[r];
            i1[r] = take ? j1 : i1[r];
        }
    }

    float lsum = 0.f;
    if ((lane & 15) == 0) {
        const int g = lane >> 4;
#pragma unroll
        for (int r = 0; r < 4; ++r) {
            const int trow = g * 4 + r;
            const int t = WB + trow;
            idx_g[t] = (ushort_t)i1[r];
            atomicAdd(&counts[i1[r]], 1u);                // native u32 atomic: cheap
            float dq = s_xsq[wv][trow] - 2.f * m1[r];
            lsum += dq;
            if (m1[r] - m2[r] < TAU_S) {                  // near-tie -> fp64 recheck
                uint_t pos = atomicAdd(flag_cnt, 1u);
                if (pos < FLAG_CAP) {
                    flags[4 * pos + 0] = t;
                    flags[4 * pos + 1] = i1[r];
                    flags[4 * pos + 2] = __float_as_int(dq);
                }
            }
        }
    }
    lsum += __shfl_xor(lsum, 16, 64);
    lsum += __shfl_xor(lsum, 32, 64);
    if (lane == 0) lossA[blockIdx.x * 4 + wv] = lsum;     // plain store, no atomic
}

// ---- store: pure streaming construction of encodings + quantized ----
__global__ __launch_bounds__(256) void vq_store(
    const ushort_t* __restrict__ idx_g, const float* __restrict__ W,
    float* __restrict__ out)
{
    const int tid = threadIdx.x;
    const int TB  = blockIdx.x * 64;
    __shared__ int s_idx[64];
    if (tid < 64) s_idx[tid] = idx_g[TB + tid];
    __syncthreads();

    // encodings: base = out + 2 + NTOK*DIM  (byte addr == 8 mod 16)
    float* enc = out + 2 + (size_t)NTOK * DIM + (size_t)TB * KCODES;
    if (tid < 255) {
        const int c = 2 + 4 * tid;                 // 16B-aligned interior
        float* p = enc + c;
        for (int r = 0; r < 64; ++r) {
            const int k = s_idx[r] - c;
            nf32x4 v;
            v.x = (k == 0) ? 1.f : 0.f;
            v.y = (k == 1) ? 1.f : 0.f;
            v.z = (k == 2) ? 1.f : 0.f;
            v.w = (k == 3) ? 1.f : 0.f;
            __builtin_nontemporal_store(v, (nf32x4*)(p));
            p += KCODES;
        }
    } else {                                       // head (cols 0,1) + tail (1022,1023)
        float* p = enc;
        for (int r = 0; r < 64; ++r) {
            const int idx = s_idx[r];
            nf32x2 h, t;
            h.x = (idx == 0)    ? 1.f : 0.f;
            h.y = (idx == 1)    ? 1.f : 0.f;
            t.x = (idx == 1022) ? 1.f : 0.f;
            t.y = (idx == 1023) ? 1.f : 0.f;
            __builtin_nontemporal_store(h, (nf32x2*)(p));
            __builtin_nontemporal_store(t, (nf32x2*)(p + 1022));
            p += KCODES;
        }
    }

    // quantized rows (out[1..]): 4B-aligned only -> scalar NT, coalesced
    for (int i = tid; i < 64 * DIM; i += 256) {
        const int r = i >> 6, c = i & 63;
        const float w = W[(size_t)s_idx[r] * DIM + c];
        __builtin_nontemporal_store(w, out + 1 + (size_t)(TB + r) * DIM + c);
    }
}

// ---- refine: fp64 full rescan of flagged (near-tie) tokens, patch outputs ----
__global__ __launch_bounds__(256) void vq_refine(
    const float* __restrict__ X, const float* __restrict__ W,
    float* __restrict__ out, uint_t* __restrict__ counts,
    double* __restrict__ lossB, const uint_t* __restrict__ flag_cnt,
    const int* __restrict__ flags)
{
    const int tid = threadIdx.x;
    const int lane = tid & 63;
    const int wv = tid >> 6;
    uint_t n = *flag_cnt; if (n > FLAG_CAP) n = FLAG_CAP;
    __shared__ float sx[DIM];
    __shared__ double sbest[4];
    __shared__ int sbi[4];
    double lcorr = 0.0;
    for (uint_t e = blockIdx.x; e < n; e += gridDim.x) {
        const int t   = flags[4 * e + 0];
        const int old = flags[4 * e + 1];
        const float dq_old = __int_as_float(flags[4 * e + 2]);
        __syncthreads();
        if (tid < DIM) sx[tid] = X[(size_t)t * DIM + tid];
        __syncthreads();
        double best = 1e300; int bi = KCODES;
        for (int k = 0; k < 4; ++k) {
            const int c = tid * 4 + k;
            const float* wr = W + (size_t)c * DIM;
            double d = 0.0;
            for (int dd = 0; dd < DIM; ++dd) {
                double diff = (double)sx[dd] - (double)wr[dd];
                d += diff * diff;
            }
            if (d < best) { best = d; bi = c; }
        }
#pragma unroll
        for (int mask = 1; mask <= 32; mask <<= 1) {
            double db = __shfl_xor(best, mask, 64);
            int    ib = __shfl_xor(bi, mask, 64);
            if (db < best || (db == best && ib < bi)) { best = db; bi = ib; }
        }
        if (lane == 0) { sbest[wv] = best; sbi[wv] = bi; }
        __syncthreads();
        if (tid == 0) {
            for (int w = 1; w < 4; ++w)
                if (sbest[w] < best || (sbest[w] == best && sbi[w] < bi)) { best = sbest[w]; bi = sbi[w]; }
            lcorr += best - (double)dq_old;               // register accumulate
            if (bi != old) {
                atomicSub(&counts[old], 1u);
                atomicAdd(&counts[bi], 1u);
                float* encp = out + 2 + (size_t)NTOK * DIM + (size_t)t * KCODES;
                encp[old] = 0.f; encp[bi] = 1.f;
                float* q = out + 1 + (size_t)t * DIM;
                for (int dd = 0; dd < DIM; ++dd) q[dd] = W[(size_t)bi * DIM + dd];
            }
        }
    }
    if (tid == 0) lossB[blockIdx.x] = lcorr;              // plain store, no atomic
}

__global__ __launch_bounds__(256) void vq_finalize(
    const uint_t* __restrict__ counts, const float* __restrict__ lossA,
    const double* __restrict__ lossB, float* __restrict__ out)
{
    int tid = threadIdx.x;
    // deterministic loss reduction: fixed strides, fixed tree
    double ls = 0.0;
    for (int i = tid; i < 8192; i += 256) ls += (double)lossA[i];
    ls += lossB[tid];
    float h = 0.f;
    for (int i = tid; i < KCODES; i += 256) {
        float p = (float)counts[i] * (1.0f / (float)NTOK);
        h += p * logf(p + 1e-10f);
    }
    __shared__ double dred[256];
    dred[tid] = ls;
    __syncthreads();
#pragma unroll
    for (int s = 128; s >= 1; s >>= 1) {
        if (tid < s) dred[tid] += dred[tid + s];
        __syncthreads();
    }
    __shared__ float red[4];
#pragma unroll
    for (int off = 32; off >= 1; off >>= 1) h += __shfl_down(h, off, 64);
    if ((tid & 63) == 0) red[tid >> 6] = h;
    __syncthreads();
    if (tid == 0) {
        float ht = red[0] + red[1] + red[2] + red[3];
        out[(size_t)NTOK * DIM + 1] = expf(-ht);                        // perplexity
        out[0] = 0.25f * (float)(dred[0] / ((double)NTOK * DIM));       // loss
    }
}

extern "C" void kernel_launch(void* const* d_in, const int* in_sizes, int n_in,
                              void* d_out, int out_size, void* d_ws, size_t ws_size,
                              hipStream_t stream) {
    const float* X = (const float*)d_in[0];
    const float* W = (const float*)d_in[1];
    float* out = (float*)d_out;
    uint_t*   counts   = (uint_t*)d_ws;
    uint_t*   flag_cnt = (uint_t*)((char*)d_ws + 4096);
    float*    lossA    = (float*)((char*)d_ws + 4112);
    double*   lossB    = (double*)((char*)d_ws + 36880);
    float*    wsq      = (float*)((char*)d_ws + 38928);
    ushort_t* Wh       = (ushort_t*)((char*)d_ws + 43024);
    ushort_t* Wl       = (ushort_t*)((char*)d_ws + 174096);
    int*      flags    = (int*)((char*)d_ws + 305168);
    ushort_t* idx_g    = (ushort_t*)((char*)d_ws + 501776);

    (void)hipMemsetAsync(d_ws, 0, 4112, stream);  // counts + flag_cnt only
    vq_prep<<<KCODES * DIM / 256, 256, 0, stream>>>(W, Wh, Wl, wsq);
    vq_argmin<<<NTOK / 64, 256, 0, stream>>>(X, Wh, Wl, wsq, idx_g,
                                             counts, lossA, flag_cnt, flags);
    vq_store<<<NTOK / 64, 256, 0, stream>>>(idx_g, W, out);
    vq_refine<<<256, 256, 0, stream>>>(X, W, out, counts, lossB, flag_cnt, flags);
    vq_finalize<<<1, 256, 0, stream>>>(counts, lossA, lossB, out);
}

// Round 6
// 454.438 us; speedup vs baseline: 1.0814x; 1.0433x over previous
//
#include <hip/hip_runtime.h>

#define NTOK     131072
#define KCODES   1024
#define DIM      64
#define TAU_S    2e-3f
#define FLAG_CAP 12288

typedef unsigned short ushort_t;
typedef unsigned int uint_t;
typedef __attribute__((ext_vector_type(8))) short short8;
typedef __attribute__((ext_vector_type(4))) float f32x4;
typedef __attribute__((ext_vector_type(4))) float nf32x4;
typedef __attribute__((ext_vector_type(2))) float nf32x2;

// ws layout (bytes):
//      0 : counts u32[1024]                       (..4096)
//   4096 : flag_cnt u32 (+pad)                    (..4112)
//   4112 : lossA f32[8192]  per-wave partials     (..36880)
//  36880 : lossB f64[256]   refine partials       (..38928)
//  38928 : wsq f32[1024]                          (..43024)
//  43024 : Wh ushort[65536]                       (..174096)
// 174096 : Wl ushort[65536]                       (..305168)
// 305168 : flags int[4*FLAG_CAP]                  (..501776)
// 501776 : idx_g ushort[131072]                   (..763920)

__device__ inline ushort_t f2bf(float f) {
    uint_t u = __float_as_uint(f);
    return (ushort_t)((u + 0x7FFFu + ((u >> 16) & 1u)) >> 16);
}
__device__ inline float bf2f(ushort_t h) { return __uint_as_float(((uint_t)h) << 16); }

__device__ inline void pack8(float4 p, float4 q, short8& h, short8& l) {
    float v[8] = {p.x, p.y, p.z, p.w, q.x, q.y, q.z, q.w};
#pragma unroll
    for (int j = 0; j < 8; ++j) {
        ushort_t hb = f2bf(v[j]);
        float hf = bf2f(hb);
        ushort_t lb = f2bf(v[j] - hf);
        h[j] = (short)hb;
        l[j] = (short)lb;
    }
}

// ---- prep: split W into bf16 hi/lo, compute wsq; block 0 zeroes counters ----
__global__ __launch_bounds__(256) void vq_prep(const float* __restrict__ W,
                                               ushort_t* __restrict__ Wh,
                                               ushort_t* __restrict__ Wl,
                                               float* __restrict__ wsq,
                                               uint_t* __restrict__ counts,
                                               uint_t* __restrict__ flag_cnt) {
    const int tid = threadIdx.x;
    if (blockIdx.x == 0) {                   // replaces in-graph hipMemsetAsync
#pragma unroll
        for (int j = 0; j < 4; ++j) counts[tid * 4 + j] = 0u;
        if (tid == 0) *flag_cnt = 0u;
    }
    int e = blockIdx.x * 256 + tid;          // 65536 elements
    float w = W[e];
    ushort_t hb = f2bf(w);
    float hf = bf2f(hb);
    ushort_t lb = f2bf(w - hf);
    Wh[e] = hb; Wl[e] = lb;
    float sq = w * w;
#pragma unroll
    for (int off = 32; off >= 1; off >>= 1) sq += __shfl_xor(sq, off, 64);
    if ((tid & 63) == 0) wsq[e >> 6] = sq;   // one wave == one row of 64
}

// ---- argmin: bf16-split MFMA scan, 64 codes per iteration (unchanged r5) ----
__global__ __launch_bounds__(256) void vq_argmin(
    const float* __restrict__ X,
    const ushort_t* __restrict__ Wh, const ushort_t* __restrict__ Wl,
    const float* __restrict__ wsq, ushort_t* __restrict__ idx_g,
    uint_t* __restrict__ counts, float* __restrict__ lossA,
    uint_t* __restrict__ flag_cnt, int* __restrict__ flags)
{
    const int tid  = threadIdx.x;
    const int lane = tid & 63;
    const int wv   = tid >> 6;
    const int row  = lane & 15;   // A-fragment row (token within wave tile)
    const int ks   = lane >> 4;   // k-slice
    const int TB   = blockIdx.x * 64;
    const int WB   = TB + wv * 16;

    const float* xr = X + (size_t)(WB + row) * DIM + ks * 8;
    float4 a0 = *(const float4*)(xr);
    float4 a1 = *(const float4*)(xr + 4);
    float4 a2 = *(const float4*)(xr + 32);
    float4 a3 = *(const float4*)(xr + 36);

    float xsq = a0.x*a0.x + a0.y*a0.y + a0.z*a0.z + a0.w*a0.w
              + a1.x*a1.x + a1.y*a1.y + a1.z*a1.z + a1.w*a1.w
              + a2.x*a2.x + a2.y*a2.y + a2.z*a2.z + a2.w*a2.w
              + a3.x*a3.x + a3.y*a3.y + a3.z*a3.z + a3.w*a3.w;
    xsq += __shfl_xor(xsq, 16, 64);
    xsq += __shfl_xor(xsq, 32, 64);   // full 64-dim xsq of token row (lane&15)

    short8 xh0, xl0, xh1, xl1;
    pack8(a0, a1, xh0, xl0);
    pack8(a2, a3, xh1, xl1);

    __shared__ float s_xsq[4][16];
    if (lane < 16) s_xsq[wv][lane] = xsq;   // same-wave producer/consumer only

    float m1[4], m2[4]; int i1[4];
#pragma unroll
    for (int r = 0; r < 4; ++r) { m1[r] = -3.4e38f; m2[r] = -3.4e38f; i1[r] = 0; }

    for (int cb = 0; cb < KCODES; cb += 64) {
        short8 bh0[4], bh1[4], bl0[4], bl1[4];
        float c0[4];
#pragma unroll
        for (int j = 0; j < 4; ++j) {
            const int col = cb + 16 * j + row;
            const ushort_t* whp = Wh + (size_t)col * DIM + ks * 8;
            const ushort_t* wlp = Wl + (size_t)col * DIM + ks * 8;
            bh0[j] = *(const short8*)(whp);
            bh1[j] = *(const short8*)(whp + 32);
            bl0[j] = *(const short8*)(wlp);
            bl1[j] = *(const short8*)(wlp + 32);
            c0[j]  = -0.5f * wsq[col];
        }
        const int cc0 = cb + row;
#pragma unroll
        for (int j = 0; j < 4; ++j) {
            f32x4 acc;
            acc[0] = c0[j]; acc[1] = c0[j]; acc[2] = c0[j]; acc[3] = c0[j];
            acc = __builtin_amdgcn_mfma_f32_16x16x32_bf16(xh0, bh0[j], acc, 0, 0, 0);
            acc = __builtin_amdgcn_mfma_f32_16x16x32_bf16(xh1, bh1[j], acc, 0, 0, 0);
            acc = __builtin_amdgcn_mfma_f32_16x16x32_bf16(xh0, bl0[j], acc, 0, 0, 0);
            acc = __builtin_amdgcn_mfma_f32_16x16x32_bf16(xh1, bl1[j], acc, 0, 0, 0);
            acc = __builtin_amdgcn_mfma_f32_16x16x32_bf16(xl0, bh0[j], acc, 0, 0, 0);
            acc = __builtin_amdgcn_mfma_f32_16x16x32_bf16(xl1, bh1[j], acc, 0, 0, 0);
            const int cc = cc0 + 16 * j;
#pragma unroll
            for (int r = 0; r < 4; ++r) {
                float v = acc[r];
                bool gt = v > m1[r];                      // strict: ties keep lower idx
                m2[r] = fmaxf(fminf(v, m1[r]), m2[r]);
                i1[r] = gt ? cc : i1[r];
                m1[r] = fmaxf(v, m1[r]);
            }
        }
    }

#pragma unroll
    for (int mask = 1; mask <= 8; mask <<= 1) {
#pragma unroll
        for (int r = 0; r < 4; ++r) {
            float v1 = __shfl_xor(m1[r], mask, 64);
            int   j1 = __shfl_xor(i1[r], mask, 64);
            float v2 = __shfl_xor(m2[r], mask, 64);
            bool take = (v1 > m1[r]) || (v1 == m1[r] && j1 < i1[r]);
            m2[r] = take ? fmaxf(m1[r], v2) : fmaxf(v1, m2[r]);
            m1[r] = take ? v1 : m1[r];
            i1[r] = take ? j1 : i1[r];
        }
    }

    float lsum = 0.f;
    if ((lane & 15) == 0) {
        const int g = lane >> 4;
#pragma unroll
        for (int r = 0; r < 4; ++r) {
            const int trow = g * 4 + r;
            const int t = WB + trow;
            idx_g[t] = (ushort_t)i1[r];
            atomicAdd(&counts[i1[r]], 1u);                // native u32 atomic
            float dq = s_xsq[wv][trow] - 2.f * m1[r];
            lsum += dq;
            if (m1[r] - m2[r] < TAU_S) {                  // near-tie -> fp64 recheck
                uint_t pos = atomicAdd(flag_cnt, 1u);
                if (pos < FLAG_CAP) {
                    flags[4 * pos + 0] = t;
                    flags[4 * pos + 1] = i1[r];
                    flags[4 * pos + 2] = __float_as_int(dq);
                }
            }
        }
    }
    lsum += __shfl_xor(lsum, 16, 64);
    lsum += __shfl_xor(lsum, 32, 64);
    if (lane == 0) lossA[blockIdx.x * 4 + wv] = lsum;     // plain store, no atomic
}

// ---- zero: fill-pattern streaming zero of the encodings region ----
// Covers elements [8388608, 142606336) with 16B plain stores (whole-grid
// contiguous per iteration, like rocclr fillBufferAligned), + 8B tail.
__global__ __launch_bounds__(256) void vq_zero(float* __restrict__ out) {
    const size_t i = (size_t)blockIdx.x * 256 + threadIdx.x;   // 524288 threads
    float* base = out + 8388608;
    nf32x4 z = {0.f, 0.f, 0.f, 0.f};
#pragma unroll 4
    for (int it = 0; it < 64; ++it) {
        nf32x4* p = (nf32x4*)(base) + (size_t)it * 524288 + i;
        *p = z;
    }
    if (blockIdx.x == 0 && threadIdx.x == 0) {
        nf32x2 z2 = {0.f, 0.f};
        *(nf32x2*)(out + 142606336) = z2;                      // last 2 elements
    }
}

// ---- scatter: the 131072 ones + quantized gather rows ----
__global__ __launch_bounds__(256) void vq_scatter(
    const ushort_t* __restrict__ idx_g, const float* __restrict__ W,
    float* __restrict__ out)
{
    const int tid = threadIdx.x;
    const int TB  = blockIdx.x * 64;
    __shared__ int s_idx[64];
    if (tid < 64) s_idx[tid] = idx_g[TB + tid];
    __syncthreads();

    if (tid < 64)   // one dirty line per token; ~34 MB RMW traffic total
        out[2 + (size_t)NTOK * DIM + (size_t)(TB + tid) * KCODES + s_idx[tid]] = 1.f;

    // quantized rows (out[1..]): coalesced scalar stores, W is L2-resident
    for (int i = tid; i < 64 * DIM; i += 256) {
        const int r = i >> 6, c = i & 63;
        out[1 + (size_t)(TB + r) * DIM + c] = W[(size_t)s_idx[r] * DIM + c];
    }
}

// ---- refine: fp64 full rescan of flagged (near-tie) tokens, patch outputs ----
__global__ __launch_bounds__(256) void vq_refine(
    const float* __restrict__ X, const float* __restrict__ W,
    float* __restrict__ out, uint_t* __restrict__ counts,
    double* __restrict__ lossB, const uint_t* __restrict__ flag_cnt,
    const int* __restrict__ flags)
{
    const int tid = threadIdx.x;
    const int lane = tid & 63;
    const int wv = tid >> 6;
    uint_t n = *flag_cnt; if (n > FLAG_CAP) n = FLAG_CAP;
    __shared__ float sx[DIM];
    __shared__ double sbest[4];
    __shared__ int sbi[4];
    double lcorr = 0.0;
    for (uint_t e = blockIdx.x; e < n; e += gridDim.x) {
        const int t   = flags[4 * e + 0];
        const int old = flags[4 * e + 1];
        const float dq_old = __int_as_float(flags[4 * e + 2]);
        __syncthreads();
        if (tid < DIM) sx[tid] = X[(size_t)t * DIM + tid];
        __syncthreads();
        double best = 1e300; int bi = KCODES;
        for (int k = 0; k < 4; ++k) {
            const int c = tid * 4 + k;
            const float* wr = W + (size_t)c * DIM;
            double d = 0.0;
            for (int dd = 0; dd < DIM; ++dd) {
                double diff = (double)sx[dd] - (double)wr[dd];
                d += diff * diff;
            }
            if (d < best) { best = d; bi = c; }
        }
#pragma unroll
        for (int mask = 1; mask <= 32; mask <<= 1) {
            double db = __shfl_xor(best, mask, 64);
            int    ib = __shfl_xor(bi, mask, 64);
            if (db < best || (db == best && ib < bi)) { best = db; bi = ib; }
        }
        if (lane == 0) { sbest[wv] = best; sbi[wv] = bi; }
        __syncthreads();
        if (tid == 0) {
            for (int w = 1; w < 4; ++w)
                if (sbest[w] < best || (sbest[w] == best && sbi[w] < bi)) { best = sbest[w]; bi = sbi[w]; }
            lcorr += best - (double)dq_old;
            if (bi != old) {
                atomicSub(&counts[old], 1u);
                atomicAdd(&counts[bi], 1u);
                float* encp = out + 2 + (size_t)NTOK * DIM + (size_t)t * KCODES;
                encp[old] = 0.f; encp[bi] = 1.f;
                float* q = out + 1 + (size_t)t * DIM;
                for (int dd = 0; dd < DIM; ++dd) q[dd] = W[(size_t)bi * DIM + dd];
            }
        }
    }
    if (tid == 0) lossB[blockIdx.x] = lcorr;
}

__global__ __launch_bounds__(256) void vq_finalize(
    const uint_t* __restrict__ counts, const float* __restrict__ lossA,
    const double* __restrict__ lossB, float* __restrict__ out)
{
    int tid = threadIdx.x;
    double ls = 0.0;                       // deterministic fixed-tree reduction
    for (int i = tid; i < 8192; i += 256) ls += (double)lossA[i];
    ls += lossB[tid];
    float h = 0.f;
    for (int i = tid; i < KCODES; i += 256) {
        float p = (float)counts[i] * (1.0f / (float)NTOK);
        h += p * logf(p + 1e-10f);
    }
    __shared__ double dred[256];
    dred[tid] = ls;
    __syncthreads();
#pragma unroll
    for (int s = 128; s >= 1; s >>= 1) {
        if (tid < s) dred[tid] += dred[tid + s];
        __syncthreads();
    }
    __shared__ float red[4];
#pragma unroll
    for (int off = 32; off >= 1; off >>= 1) h += __shfl_down(h, off, 64);
    if ((tid & 63) == 0) red[tid >> 6] = h;
    __syncthreads();
    if (tid == 0) {
        float ht = red[0] + red[1] + red[2] + red[3];
        out[(size_t)NTOK * DIM + 1] = expf(-ht);                        // perplexity
        out[0] = 0.25f * (float)(dred[0] / ((double)NTOK * DIM));       // loss
    }
}

extern "C" void kernel_launch(void* const* d_in, const int* in_sizes, int n_in,
                              void* d_out, int out_size, void* d_ws, size_t ws_size,
                              hipStream_t stream) {
    const float* X = (const float*)d_in[0];
    const float* W = (const float*)d_in[1];
    float* out = (float*)d_out;
    uint_t*   counts   = (uint_t*)d_ws;
    uint_t*   flag_cnt = (uint_t*)((char*)d_ws + 4096);
    float*    lossA    = (float*)((char*)d_ws + 4112);
    double*   lossB    = (double*)((char*)d_ws + 36880);
    float*    wsq      = (float*)((char*)d_ws + 38928);
    ushort_t* Wh       = (ushort_t*)((char*)d_ws + 43024);
    ushort_t* Wl       = (ushort_t*)((char*)d_ws + 174096);
    int*      flags    = (int*)((char*)d_ws + 305168);
    ushort_t* idx_g    = (ushort_t*)((char*)d_ws + 501776);

    vq_prep<<<KCODES * DIM / 256, 256, 0, stream>>>(W, Wh, Wl, wsq, counts, flag_cnt);
    vq_argmin<<<NTOK / 64, 256, 0, stream>>>(X, Wh, Wl, wsq, idx_g,
                                             counts, lossA, flag_cnt, flags);
    vq_zero<<<2048, 256, 0, stream>>>(out);
    vq_scatter<<<NTOK / 64, 256, 0, stream>>>(idx_g, W, out);
    vq_refine<<<256, 256, 0, stream>>>(X, W, out, counts, lossB, flag_cnt, flags);
    vq_finalize<<<1, 256, 0, stream>>>(counts, lossA, lossB, out);
}

// Round 7
// 333.890 us; speedup vs baseline: 1.4718x; 1.3610x over previous
//
#include <hip/hip_runtime.h>

#define NTOK     131072
#define KCODES   1024
#define DIM      64
#define TAU_S    2e-3f
#define FLAG_CAP 12288

typedef unsigned short ushort_t;
typedef unsigned int uint_t;
typedef unsigned char uchar_t;
typedef __attribute__((ext_vector_type(8))) short short8;
typedef __attribute__((ext_vector_type(4))) float f32x4;
typedef __attribute__((ext_vector_type(4))) float nf32x4;
typedef __attribute__((ext_vector_type(2))) float nf32x2;

// ws layout (bytes):
//      0 : counts u32[1024]                 (..4096)
//   4096 : flag_cnt u32 (+pad)              (..4112)
//   4112 : lossA f32[4096] per-wave         (..20496)
//  20496 : lossB f64[256]  refine partials  (..22544)
//  22544 : wsq f32[1024]                    (..26640)
//  28672 : Wst uchar[262144] staged W       (..290816)
// 290816 : flags int[4*FLAG_CAP]            (..487424)
// 487424 : idx_g ushort[131072]             (..749568)
//
// Staged layout: for code k (group g=k>>5, c=k&31), dim d (slice s=d>>3, p=d&7):
//   byte = g*8192 + half*4096 + s*512 + ((c ^ (s&3)))*16 + p*2   (half: 0=hi,1=lo)
// This makes (i) block staging a LINEAR 8KB copy and (ii) per-lane MFMA-fragment
// ds_read_b128 addresses = ks*512 + j*256 + ((col16^ks))*16 (+{0,2048,4096,6144}),
// XOR-swizzled so the 4 ks-groups of a wave hit different banks (G4).

__device__ inline ushort_t f2bf(float f) {
    uint_t u = __float_as_uint(f);
    return (ushort_t)((u + 0x7FFFu + ((u >> 16) & 1u)) >> 16);
}
__device__ inline float bf2f(ushort_t h) { return __uint_as_float(((uint_t)h) << 16); }

__device__ inline void pack8(float4 p, float4 q, short8& h, short8& l) {
    float v[8] = {p.x, p.y, p.z, p.w, q.x, q.y, q.z, q.w};
#pragma unroll
    for (int j = 0; j < 8; ++j) {
        ushort_t hb = f2bf(v[j]);
        float hf = bf2f(hb);
        ushort_t lb = f2bf(v[j] - hf);
        h[j] = (short)hb;
        l[j] = (short)lb;
    }
}

// ---- prep: split W into staged bf16 hi/lo layout, compute wsq, zero counters ----
__global__ __launch_bounds__(256) void vq_prep(const float* __restrict__ W,
                                               uchar_t* __restrict__ Wst,
                                               float* __restrict__ wsq,
                                               uint_t* __restrict__ counts,
                                               uint_t* __restrict__ flag_cnt) {
    const int tid = threadIdx.x;
    if (blockIdx.x == 0) {
#pragma unroll
        for (int j = 0; j < 4; ++j) counts[tid * 4 + j] = 0u;
        if (tid == 0) *flag_cnt = 0u;
    }
    const int e = blockIdx.x * 256 + tid;      // 65536 elements
    const int k = e >> 6, d = e & 63;
    const float w = W[e];
    const ushort_t hb = f2bf(w);
    const float hf = bf2f(hb);
    const ushort_t lb = f2bf(w - hf);
    const int g = k >> 5, c = k & 31, s = d >> 3, p = d & 7;
    const size_t base = (size_t)g * 8192 + (size_t)s * 512
                      + (size_t)(c ^ (s & 3)) * 16 + (size_t)p * 2;
    *(ushort_t*)(Wst + base)        = hb;
    *(ushort_t*)(Wst + base + 4096) = lb;
    float sq = w * w;
#pragma unroll
    for (int off = 32; off >= 1; off >>= 1) sq += __shfl_xor(sq, off, 64);
    if ((tid & 63) == 0) wsq[e >> 6] = sq;
}

// ---- argmin: LDS-staged, double-buffered, 32 tokens/wave, 128/block ----
__global__ __launch_bounds__(256) void vq_argmin(
    const float* __restrict__ X, const uchar_t* __restrict__ Wst,
    const float* __restrict__ wsq_g, ushort_t* __restrict__ idx_g,
    uint_t* __restrict__ counts, float* __restrict__ lossA,
    uint_t* __restrict__ flag_cnt, int* __restrict__ flags)
{
    const int tid   = threadIdx.x;
    const int lane  = tid & 63;
    const int wv    = tid >> 6;
    const int col16 = lane & 15;        // fragment row/col residue
    const int ks    = lane >> 4;        // k-slice
    const int WB    = blockIdx.x * 128 + wv * 32;

    __shared__ __align__(16) char sbuf[2][8192];
    __shared__ float s_wsq[KCODES];
    __shared__ float s_xsq[4][2][16];

    for (int i = tid; i < KCODES; i += 256) s_wsq[i] = -0.5f * wsq_g[i];

    // A fragments for two 16-token tiles, bf16 hi/lo
    short8 xh[2][2], xl[2][2];
#pragma unroll
    for (int t = 0; t < 2; ++t) {
        const float* xr = X + (size_t)(WB + t * 16 + col16) * DIM + ks * 8;
        float4 a0 = *(const float4*)(xr);
        float4 a1 = *(const float4*)(xr + 4);
        float4 a2 = *(const float4*)(xr + 32);
        float4 a3 = *(const float4*)(xr + 36);
        float xsq = a0.x*a0.x + a0.y*a0.y + a0.z*a0.z + a0.w*a0.w
                  + a1.x*a1.x + a1.y*a1.y + a1.z*a1.z + a1.w*a1.w
                  + a2.x*a2.x + a2.y*a2.y + a2.z*a2.z + a2.w*a2.w
                  + a3.x*a3.x + a3.y*a3.y + a3.z*a3.z + a3.w*a3.w;
        xsq += __shfl_xor(xsq, 16, 64);
        xsq += __shfl_xor(xsq, 32, 64);
        if (lane < 16) s_xsq[wv][t][lane] = xsq;
        pack8(a0, a1, xh[t][0], xl[t][0]);
        pack8(a2, a3, xh[t][1], xl[t][1]);
    }

    // staging regs + prologue (group 0)
    short8 p0, p1;
    {
        const short8* src = (const short8*)(Wst + (size_t)tid * 16);
        p0 = src[0]; p1 = src[256];
        short8* dst = (short8*)(&sbuf[0][tid * 16]);
        dst[0] = p0; dst[256] = p1;
    }
    __syncthreads();

    float m1[2][4], m2[2][4]; int i1[2][4];
#pragma unroll
    for (int t = 0; t < 2; ++t)
#pragma unroll
        for (int r = 0; r < 4; ++r) { m1[t][r] = -3.4e38f; m2[t][r] = -3.4e38f; i1[t][r] = 0; }

    const int rb = ks * 512 + ((col16 ^ ks) * 16);

    for (int g = 0; g < 32; ++g) {
        const int cb = g * 32;
        const int b  = g & 1;
        if (g < 31) {                               // issue next-group loads early
            const short8* src = (const short8*)(Wst + (size_t)(g + 1) * 8192 + (size_t)tid * 16);
            p0 = src[0]; p1 = src[256];
        }
        const char* buf = sbuf[b];
#pragma unroll
        for (int j = 0; j < 2; ++j) {
            const int off = rb + j * 256;
            short8 bh0 = *(const short8*)(buf + off);
            short8 bh1 = *(const short8*)(buf + off + 2048);
            short8 bl0 = *(const short8*)(buf + off + 4096);
            short8 bl1 = *(const short8*)(buf + off + 6144);
            const float c0 = s_wsq[cb + j * 16 + col16];
            f32x4 acc0, acc1;
            acc0[0] = c0; acc0[1] = c0; acc0[2] = c0; acc0[3] = c0;
            acc1 = acc0;
            acc0 = __builtin_amdgcn_mfma_f32_16x16x32_bf16(xh[0][0], bh0, acc0, 0, 0, 0);
            acc0 = __builtin_amdgcn_mfma_f32_16x16x32_bf16(xh[0][1], bh1, acc0, 0, 0, 0);
            acc0 = __builtin_amdgcn_mfma_f32_16x16x32_bf16(xh[0][0], bl0, acc0, 0, 0, 0);
            acc0 = __builtin_amdgcn_mfma_f32_16x16x32_bf16(xh[0][1], bl1, acc0, 0, 0, 0);
            acc0 = __builtin_amdgcn_mfma_f32_16x16x32_bf16(xl[0][0], bh0, acc0, 0, 0, 0);
            acc0 = __builtin_amdgcn_mfma_f32_16x16x32_bf16(xl[0][1], bh1, acc0, 0, 0, 0);
            acc1 = __builtin_amdgcn_mfma_f32_16x16x32_bf16(xh[1][0], bh0, acc1, 0, 0, 0);
            acc1 = __builtin_amdgcn_mfma_f32_16x16x32_bf16(xh[1][1], bh1, acc1, 0, 0, 0);
            acc1 = __builtin_amdgcn_mfma_f32_16x16x32_bf16(xh[1][0], bl0, acc1, 0, 0, 0);
            acc1 = __builtin_amdgcn_mfma_f32_16x16x32_bf16(xh[1][1], bl1, acc1, 0, 0, 0);
            acc1 = __builtin_amdgcn_mfma_f32_16x16x32_bf16(xl[1][0], bh0, acc1, 0, 0, 0);
            acc1 = __builtin_amdgcn_mfma_f32_16x16x32_bf16(xl[1][1], bh1, acc1, 0, 0, 0);
            const int cc = cb + j * 16 + col16;
#pragma unroll
            for (int r = 0; r < 4; ++r) {
                float v = acc0[r];
                bool gt = v > m1[0][r];
                m2[0][r] = fmaxf(fminf(v, m1[0][r]), m2[0][r]);
                i1[0][r] = gt ? cc : i1[0][r];
                m1[0][r] = fmaxf(v, m1[0][r]);
            }
#pragma unroll
            for (int r = 0; r < 4; ++r) {
                float v = acc1[r];
                bool gt = v > m1[1][r];
                m2[1][r] = fmaxf(fminf(v, m1[1][r]), m2[1][r]);
                i1[1][r] = gt ? cc : i1[1][r];
                m1[1][r] = fmaxf(v, m1[1][r]);
            }
        }
        if (g < 31) {                               // write next group to other buffer
            short8* dst = (short8*)(&sbuf[b ^ 1][tid * 16]);
            dst[0] = p0; dst[256] = p1;
            __syncthreads();
        }
    }

    // merge top-2 across the 16 code-residue lanes of each ks group
#pragma unroll
    for (int mask = 1; mask <= 8; mask <<= 1) {
#pragma unroll
        for (int t = 0; t < 2; ++t)
#pragma unroll
        for (int r = 0; r < 4; ++r) {
            float v1 = __shfl_xor(m1[t][r], mask, 64);
            int   j1 = __shfl_xor(i1[t][r], mask, 64);
            float v2 = __shfl_xor(m2[t][r], mask, 64);
            bool take = (v1 > m1[t][r]) || (v1 == m1[t][r] && j1 < i1[t][r]);
            m2[t][r] = take ? fmaxf(m1[t][r], v2) : fmaxf(v1, m2[t][r]);
            m1[t][r] = take ? v1 : m1[t][r];
            i1[t][r] = take ? j1 : i1[t][r];
        }
    }

    float lsum = 0.f;
    if (col16 == 0) {
#pragma unroll
        for (int t = 0; t < 2; ++t)
#pragma unroll
        for (int r = 0; r < 4; ++r) {
            const int trow = ks * 4 + r;
            const int tok = WB + t * 16 + trow;
            idx_g[tok] = (ushort_t)i1[t][r];
            atomicAdd(&counts[i1[t][r]], 1u);
            float dq = s_xsq[wv][t][trow] - 2.f * m1[t][r];
            lsum += dq;
            if (m1[t][r] - m2[t][r] < TAU_S) {
                uint_t pos = atomicAdd(flag_cnt, 1u);
                if (pos < FLAG_CAP) {
                    flags[4 * pos + 0] = tok;
                    flags[4 * pos + 1] = i1[t][r];
                    flags[4 * pos + 2] = __float_as_int(dq);
                }
            }
        }
    }
    lsum += __shfl_xor(lsum, 16, 64);
    lsum += __shfl_xor(lsum, 32, 64);
    if (lane == 0) lossA[blockIdx.x * 4 + wv] = lsum;
}

// ---- zero: fill-pattern streaming zero of the encodings region ----
__global__ __launch_bounds__(256) void vq_zero(float* __restrict__ out) {
    const size_t i = (size_t)blockIdx.x * 256 + threadIdx.x;   // 524288 threads
    float* base = out + 8388608;
    nf32x4 z = {0.f, 0.f, 0.f, 0.f};
#pragma unroll 4
    for (int it = 0; it < 64; ++it) {
        nf32x4* p = (nf32x4*)(base) + (size_t)it * 524288 + i;
        *p = z;
    }
    if (blockIdx.x == 0 && threadIdx.x == 0) {
        nf32x2 z2 = {0.f, 0.f};
        *(nf32x2*)(out + 142606336) = z2;                      // last 2 elements
    }
}

// ---- scatter: the 131072 ones + quantized gather rows ----
__global__ __launch_bounds__(256) void vq_scatter(
    const ushort_t* __restrict__ idx_g, const float* __restrict__ W,
    float* __restrict__ out)
{
    const int tid = threadIdx.x;
    const int TB  = blockIdx.x * 64;
    __shared__ int s_idx[64];
    if (tid < 64) s_idx[tid] = idx_g[TB + tid];
    __syncthreads();

    if (tid < 64)
        out[2 + (size_t)NTOK * DIM + (size_t)(TB + tid) * KCODES + s_idx[tid]] = 1.f;

    for (int i = tid; i < 64 * DIM; i += 256) {
        const int r = i >> 6, c = i & 63;
        out[1 + (size_t)(TB + r) * DIM + c] = W[(size_t)s_idx[r] * DIM + c];
    }
}

// ---- refine: fp64 full rescan of flagged (near-tie) tokens, patch outputs ----
__global__ __launch_bounds__(256) void vq_refine(
    const float* __restrict__ X, const float* __restrict__ W,
    float* __restrict__ out, uint_t* __restrict__ counts,
    double* __restrict__ lossB, const uint_t* __restrict__ flag_cnt,
    const int* __restrict__ flags)
{
    const int tid = threadIdx.x;
    const int lane = tid & 63;
    const int wv = tid >> 6;
    uint_t n = *flag_cnt; if (n > FLAG_CAP) n = FLAG_CAP;
    __shared__ float sx[DIM];
    __shared__ double sbest[4];
    __shared__ int sbi[4];
    double lcorr = 0.0;
    for (uint_t e = blockIdx.x; e < n; e += gridDim.x) {
        const int t   = flags[4 * e + 0];
        const int old = flags[4 * e + 1];
        const float dq_old = __int_as_float(flags[4 * e + 2]);
        __syncthreads();
        if (tid < DIM) sx[tid] = X[(size_t)t * DIM + tid];
        __syncthreads();
        double best = 1e300; int bi = KCODES;
        for (int k = 0; k < 4; ++k) {
            const int c = tid * 4 + k;
            const float* wr = W + (size_t)c * DIM;
            double d = 0.0;
            for (int dd = 0; dd < DIM; ++dd) {
                double diff = (double)sx[dd] - (double)wr[dd];
                d += diff * diff;
            }
            if (d < best) { best = d; bi = c; }
        }
#pragma unroll
        for (int mask = 1; mask <= 32; mask <<= 1) {
            double db = __shfl_xor(best, mask, 64);
            int    ib = __shfl_xor(bi, mask, 64);
            if (db < best || (db == best && ib < bi)) { best = db; bi = ib; }
        }
        if (lane == 0) { sbest[wv] = best; sbi[wv] = bi; }
        __syncthreads();
        if (tid == 0) {
            for (int w = 1; w < 4; ++w)
                if (sbest[w] < best || (sbest[w] == best && sbi[w] < bi)) { best = sbest[w]; bi = sbi[w]; }
            lcorr += best - (double)dq_old;
            if (bi != old) {
                atomicSub(&counts[old], 1u);
                atomicAdd(&counts[bi], 1u);
                float* encp = out + 2 + (size_t)NTOK * DIM + (size_t)t * KCODES;
                encp[old] = 0.f; encp[bi] = 1.f;
                float* q = out + 1 + (size_t)t * DIM;
                for (int dd = 0; dd < DIM; ++dd) q[dd] = W[(size_t)bi * DIM + dd];
            }
        }
    }
    if (tid == 0) lossB[blockIdx.x] = lcorr;
}

__global__ __launch_bounds__(256) void vq_finalize(
    const uint_t* __restrict__ counts, const float* __restrict__ lossA,
    const double* __restrict__ lossB, float* __restrict__ out)
{
    int tid = threadIdx.x;
    double ls = 0.0;                       // deterministic fixed-tree reduction
    for (int i = tid; i < 4096; i += 256) ls += (double)lossA[i];
    ls += lossB[tid];
    float h = 0.f;
    for (int i = tid; i < KCODES; i += 256) {
        float p = (float)counts[i] * (1.0f / (float)NTOK);
        h += p * logf(p + 1e-10f);
    }
    __shared__ double dred[256];
    dred[tid] = ls;
    __syncthreads();
#pragma unroll
    for (int s = 128; s >= 1; s >>= 1) {
        if (tid < s) dred[tid] += dred[tid + s];
        __syncthreads();
    }
    __shared__ float red[4];
#pragma unroll
    for (int off = 32; off >= 1; off >>= 1) h += __shfl_down(h, off, 64);
    if ((tid & 63) == 0) red[tid >> 6] = h;
    __syncthreads();
    if (tid == 0) {
        float ht = red[0] + red[1] + red[2] + red[3];
        out[(size_t)NTOK * DIM + 1] = expf(-ht);                        // perplexity
        out[0] = 0.25f * (float)(dred[0] / ((double)NTOK * DIM));       // loss
    }
}

extern "C" void kernel_launch(void* const* d_in, const int* in_sizes, int n_in,
                              void* d_out, int out_size, void* d_ws, size_t ws_size,
                              hipStream_t stream) {
    const float* X = (const float*)d_in[0];
    const float* W = (const float*)d_in[1];
    float* out = (float*)d_out;
    uint_t*   counts   = (uint_t*)d_ws;
    uint_t*   flag_cnt = (uint_t*)((char*)d_ws + 4096);
    float*    lossA    = (float*)((char*)d_ws + 4112);
    double*   lossB    = (double*)((char*)d_ws + 20496);
    float*    wsq      = (float*)((char*)d_ws + 22544);
    uchar_t*  Wst      = (uchar_t*)((char*)d_ws + 28672);
    int*      flags    = (int*)((char*)d_ws + 290816);
    ushort_t* idx_g    = (ushort_t*)((char*)d_ws + 487424);

    vq_prep<<<256, 256, 0, stream>>>(W, Wst, wsq, counts, flag_cnt);
    vq_argmin<<<NTOK / 128, 256, 0, stream>>>(X, Wst, wsq, idx_g,
                                              counts, lossA, flag_cnt, flags);
    vq_zero<<<2048, 256, 0, stream>>>(out);
    vq_scatter<<<NTOK / 64, 256, 0, stream>>>(idx_g, W, out);
    vq_refine<<<256, 256, 0, stream>>>(X, W, out, counts, lossB, flag_cnt, flags);
    vq_finalize<<<1, 256, 0, stream>>>(counts, lossA, lossB, out);
}